// Round 9
// baseline (550.469 us; speedup 1.0000x reference)
//
#include <hip/hip_runtime.h>

#define N_USERS 200000
#define N_ITEMS 100000
#define N_NODES 300000
#define DIM 64
#define N_INTER 1000000
#define N_EDGES (2 * N_INTER)

#define SBLK 1024                      // nodes per scan block
#define NSB ((N_NODES + SBLK - 1) / SBLK)             // 293

#define NPW 8                          // nodes (rows) per wave in gather
#define NWAVE ((N_NODES + NPW - 1) / NPW)             // 37500
#define GATHER_THREADS (NWAVE * 64)                   // 2,400,000

typedef unsigned short bf16_t;
typedef unsigned int u32;

static __device__ __forceinline__ bf16_t f2bf(float f) {
    union { float f; u32 u; } v; v.f = f;
    u32 r = v.u + 0x7FFFu + ((v.u >> 16) & 1u);
    return (bf16_t)(r >> 16);
}
static __device__ __forceinline__ float bflo(u32 v) {   // low bf16 of a packed dword
    union { u32 u; float f; } x; x.u = v << 16; return x.f;
}
static __device__ __forceinline__ float bfhi(u32 v) {   // high bf16 of a packed dword
    union { u32 u; float f; } x; x.u = v & 0xFFFF0000u; return x.f;
}
static __device__ __forceinline__ u32 pack_bf16(float lo, float hi) {   // RNE, = f2bf pair
    u32 r;
    asm("v_cvt_pk_bf16_f32 %0, %1, %2" : "=v"(r) : "v"(lo), "v"(hi));
    return r;
}

// ---------------- 1. degree count: direct global atomics ----------------
__global__ void deg_kernel(const int* __restrict__ uid, const int* __restrict__ iid,
                           u32* __restrict__ deg) {
    int k = blockIdx.x * blockDim.x + threadIdx.x;
    if (k < N_INTER) {
        int u = uid[k];
        int it = N_USERS + iid[k];
        atomicAdd(&deg[it], 1u);
        atomicAdd(&deg[u], 1u);
    }
}

// ---------------- 2a. per-block partial sums of deg ----------------
__global__ void s1_kernel(const u32* __restrict__ deg, u32* __restrict__ bsum) {
    __shared__ u32 red[256];
    int b = blockIdx.x, t = threadIdx.x;
    int base = b * SBLK;
    u32 s = 0;
    #pragma unroll
    for (int j = 0; j < 4; ++j) {
        int idx = base + t + j * 256;
        if (idx < N_NODES) s += deg[idx];
    }
    red[t] = s;
    __syncthreads();
    for (int off = 128; off > 0; off >>= 1) {
        if (t < off) red[t] += red[t + off];
        __syncthreads();
    }
    if (t == 0) bsum[b] = red[0];
}

// ---------------- 2b. scan block sums -> block bases ----------------
__global__ void s2_kernel(const u32* __restrict__ bsum, u32* __restrict__ bbase,
                          u32* __restrict__ rowptr) {
    __shared__ u32 buf[2][512];
    int t = threadIdx.x;               // 512 threads >= NSB
    u32 v0 = (t < NSB) ? bsum[t] : 0u;
    buf[0][t] = v0;
    __syncthreads();
    int s = 0;
    for (int off = 1; off < 512; off <<= 1) {
        u32 v = buf[s][t];
        if (t >= off) v += buf[s][t - off];
        buf[1 - s][t] = v;
        __syncthreads();
        s = 1 - s;
    }
    if (t < NSB) bbase[t] = buf[s][t] - v0;
    if (t == 0) rowptr[N_NODES] = N_EDGES;
}

// ---------------- 2c. local scan + base -> rowptr, cursors, dinv ----------------
__global__ void s3_kernel(const u32* __restrict__ deg, const u32* __restrict__ bbase,
                          u32* __restrict__ rowptr, u32* __restrict__ gcur,
                          float* __restrict__ dinv) {
    __shared__ u32 sb[2][SBLK];
    int b = blockIdx.x, t = threadIdx.x;   // 256 threads
    int base = b * SBLK;
    u32 v[4];
    #pragma unroll
    for (int j = 0; j < 4; ++j) {
        int idx = t + j * 256;
        int node = base + idx;
        v[j] = (node < N_NODES) ? deg[node] : 0u;
        sb[0][idx] = v[j];
    }
    __syncthreads();
    int s = 0;
    for (int off = 1; off < SBLK; off <<= 1) {
        #pragma unroll
        for (int j = 0; j < 4; ++j) {
            int idx = t + j * 256;
            u32 x = sb[s][idx];
            if (idx >= off) x += sb[s][idx - off];
            sb[1 - s][idx] = x;
        }
        __syncthreads();
        s = 1 - s;
    }
    u32 bb = bbase[b];
    #pragma unroll
    for (int j = 0; j < 4; ++j) {
        int idx = t + j * 256;
        int node = base + idx;
        if (node < N_NODES) {
            u32 rp = bb + (sb[s][idx] - v[j]);   // exclusive
            rowptr[node] = rp;
            gcur[node] = rp;
            dinv[node] = v[j] ? rsqrtf((float)v[j]) : 0.0f;
        }
    }
}

// ---------------- 3. place: direct scatter into ecol via atomic cursors ----------------
// Random 8B writes land in L2/MALL (byte-masked sectors, no RFO) -> eventual
// writeback = touched lines only. Eliminates bdata/col/csr entirely.
__global__ void place_kernel(const int* __restrict__ uid, const int* __restrict__ iid,
                             const float* __restrict__ dinv, u32* __restrict__ gcur,
                             int2* __restrict__ ecol) {
    int k = blockIdx.x * blockDim.x + threadIdx.x;
    if (k < N_INTER) {
        int u = uid[k];
        int it = N_USERS + iid[k];
        float du = dinv[u];
        float di = dinv[it];
        u32 p1 = atomicAdd(&gcur[it], 1u);
        ecol[p1] = make_int2(u, __float_as_int(du));
        u32 p2 = atomicAdd(&gcur[u], 1u);
        ecol[p2] = make_int2(it, __float_as_int(di));
    }
}

// ---------------- init: fp32 inputs -> bf16 layer-0 buffer ----------------
__global__ void init_kernel(const float4* __restrict__ ue, const float4* __restrict__ ie,
                            ushort4* __restrict__ cur) {
    int idx = blockIdx.x * blockDim.x + threadIdx.x;
    if (idx < N_NODES * 16) {
        float4 v = (idx < N_USERS * 16) ? ue[idx] : ie[idx - N_USERS * 16];
        ushort4 h;
        h.x = f2bf(v.x); h.y = f2bf(v.y); h.z = f2bf(v.z); h.w = f2bf(v.w);
        cur[idx] = h;
    }
}

// ---------------- gather SpMM: row-pair per wave, scalar edge records (R5) ------------
// One wave owns an 8-row strip; rows are processed in PAIRS: lanes 0-31
// accumulate row 2r (2 bf16 cols/lane via one u32), lanes 32-63 row 2r+1.
// Edge records come from SCALAR loads (uniform index -> s_load_dwordx2,
// scalar-cache hits), so the only vector-memory op in the loop is the gather
// itself: ONE wave64 dword load covers BOTH rows' 128B and the two acc chains
// double MLP. Inner loop unrolled x4 -> 4 gathers in flight/wave (verified
// optimum; 8-deep regressed in R8). Tail slots clamp to a valid edge (w=0).
__global__ void gather_kernel(const u32* __restrict__ rowptr, const int2* __restrict__ ecol,
                              const float* __restrict__ dinv,
                              const u32* __restrict__ cur, u32* __restrict__ nxt) {
    int wid = (blockIdx.x * blockDim.x + threadIdx.x) >> 6;
    int lane = threadIdx.x & 63;
    int n0 = __builtin_amdgcn_readfirstlane(wid * NPW);
    if (n0 >= N_NODES) return;
    u32 rp[NPW + 1];
    #pragma unroll
    for (int i = 0; i <= NPW; ++i) rp[i] = rowptr[n0 + i];   // uniform -> s_loads
    bool hi = (lane >> 5) != 0;
    u32 c = (u32)(lane & 31);
    #pragma unroll
    for (int pr = 0; pr < NPW; pr += 2) {
        u32 rsA = rp[pr],     lA = rp[pr + 1] - rp[pr];
        u32 rsB = rp[pr + 1], lB = rp[pr + 2] - rp[pr + 1];
        u32 mx = lA > lB ? lA : lB;
        float a0 = 0.0f, a1 = 0.0f;
        for (u32 p = 0; p < mx; p += 4) {
            #pragma unroll
            for (int q = 0; q < 4; ++q) {
                u32 st = p + (u32)q;
                u32 iA = rsA + st; if (iA >= (u32)N_EDGES) iA = N_EDGES - 1u;
                u32 iB = rsB + st; if (iB >= (u32)N_EDGES) iB = N_EDGES - 1u;
                iA = __builtin_amdgcn_readfirstlane((int)iA);
                iB = __builtin_amdgcn_readfirstlane((int)iB);
                int2 eA = ecol[iA];                    // uniform -> s_load_dwordx2
                int2 eB = ecol[iB];
                u32 wAu = (st < lA) ? (u32)eA.y : 0u;  // uniform -> s_cselect
                u32 wBu = (st < lB) ? (u32)eB.y : 0u;
                u32 srow = hi ? (u32)eB.x : (u32)eA.x;           // v_cndmask
                float wf = __uint_as_float(hi ? wBu : wAu);       // v_cndmask
                u32 v = cur[(srow << 5) + c];
                a0 += wf * bflo(v);
                a1 += wf * bfhi(v);
            }
        }
        float sc = hi ? dinv[n0 + pr + 1] : dinv[n0 + pr];        // uniform loads + sel
        u32 orow = (((u32)(n0 + pr) + (hi ? 1u : 0u)) << 5) + c;  // 2 rows = 256B store
        nxt[orow] = pack_bf16(sc * a0, sc * a1);
    }
}

// ---------------- layer-3 gather fused with final combine ----------------
__global__ void gather_final_kernel(const u32* __restrict__ rowptr, const int2* __restrict__ ecol,
                                    const float* __restrict__ dinv,
                                    const u32* __restrict__ b1, const u32* __restrict__ b2,
                                    const float* __restrict__ ue, const float* __restrict__ ie,
                                    float* __restrict__ out) {
    int wid = (blockIdx.x * blockDim.x + threadIdx.x) >> 6;
    int lane = threadIdx.x & 63;
    int n0 = __builtin_amdgcn_readfirstlane(wid * NPW);
    if (n0 >= N_NODES) return;
    u32 rp[NPW + 1];
    #pragma unroll
    for (int i = 0; i <= NPW; ++i) rp[i] = rowptr[n0 + i];
    bool hi = (lane >> 5) != 0;
    u32 c = (u32)(lane & 31);
    #pragma unroll
    for (int pr = 0; pr < NPW; pr += 2) {
        u32 rsA = rp[pr],     lA = rp[pr + 1] - rp[pr];
        u32 rsB = rp[pr + 1], lB = rp[pr + 2] - rp[pr + 1];
        u32 mx = lA > lB ? lA : lB;
        float a0 = 0.0f, a1 = 0.0f;
        for (u32 p = 0; p < mx; p += 4) {
            #pragma unroll
            for (int q = 0; q < 4; ++q) {
                u32 st = p + (u32)q;
                u32 iA = rsA + st; if (iA >= (u32)N_EDGES) iA = N_EDGES - 1u;
                u32 iB = rsB + st; if (iB >= (u32)N_EDGES) iB = N_EDGES - 1u;
                iA = __builtin_amdgcn_readfirstlane((int)iA);
                iB = __builtin_amdgcn_readfirstlane((int)iB);
                int2 eA = ecol[iA];
                int2 eB = ecol[iB];
                u32 wAu = (st < lA) ? (u32)eA.y : 0u;
                u32 wBu = (st < lB) ? (u32)eB.y : 0u;
                u32 srow = hi ? (u32)eB.x : (u32)eA.x;
                float wf = __uint_as_float(hi ? wBu : wAu);
                u32 v = b2[(srow << 5) + c];
                a0 += wf * bflo(v);
                a1 += wf * bfhi(v);
            }
        }
        int n = n0 + pr + (hi ? 1 : 0);
        float sc = hi ? dinv[n0 + pr + 1] : dinv[n0 + pr];
        u32 o32 = (((u32)n) << 5) + c;
        u32 v1 = b1[o32], v2 = b2[o32];
        float2 e0 = (n < N_USERS) ? ((const float2*)ue)[o32]
                                  : ((const float2*)ie)[o32 - (u32)N_USERS * 32u];
        float ox = (e0.x + bflo(v1) + bflo(v2) + sc * a0) * 0.25f;
        float oy = (e0.y + bfhi(v1) + bfhi(v2) + sc * a1) * 0.25f;
        ((float2*)out)[o32] = make_float2(ox, oy);
    }
}

extern "C" void kernel_launch(void* const* d_in, const int* in_sizes, int n_in,
                              void* d_out, int out_size, void* d_ws, size_t ws_size,
                              hipStream_t stream) {
    const float* ue = (const float*)d_in[0];
    const float* ie = (const float*)d_in[1];
    const int* uid = (const int*)d_in[2];
    const int* iid = (const int*)d_in[3];
    float* out = (float*)d_out;

    char* ws = (char*)d_ws;
    size_t off = 0;
    auto alloc = [&](size_t bytes) { char* p = ws + off; off = (off + bytes + 255) & ~(size_t)255; return p; };
    u32*    deg     = (u32*)alloc((size_t)N_NODES * 4);
    u32*    bsum    = (u32*)alloc((size_t)NSB * 4);
    u32*    bbase   = (u32*)alloc((size_t)NSB * 4);
    u32*    rowptr  = (u32*)alloc((size_t)(N_NODES + 1) * 4);
    u32*    gcur    = (u32*)alloc((size_t)N_NODES * 4);
    float*  dinv    = (float*)alloc((size_t)N_NODES * 4);
    int2*   ecol    = (int2*)alloc((size_t)N_EDGES * 8);        // 16 MB
    bf16_t* buf0    = (bf16_t*)alloc((size_t)N_NODES * DIM * 2);
    bf16_t* buf1    = (bf16_t*)alloc((size_t)N_NODES * DIM * 2);
    bf16_t* buf2    = (bf16_t*)alloc((size_t)N_NODES * DIM * 2);

    // --- CSR build: direct atomic scatter (no bucketing, no intermediate arrays) ---
    hipMemsetAsync(deg, 0, (size_t)N_NODES * 4, stream);
    deg_kernel<<<(N_INTER + 255) / 256, 256, 0, stream>>>(uid, iid, deg);
    s1_kernel<<<NSB, 256, 0, stream>>>(deg, bsum);
    s2_kernel<<<1, 512, 0, stream>>>(bsum, bbase, rowptr);
    s3_kernel<<<NSB, 256, 0, stream>>>(deg, bbase, rowptr, gcur, dinv);
    place_kernel<<<(N_INTER + 255) / 256, 256, 0, stream>>>(uid, iid, dinv, gcur, ecol);

    // --- init (fp32 -> bf16 layer 0) ---
    init_kernel<<<(N_NODES * 16 + 255) / 256, 256, 0, stream>>>(
        (const float4*)ue, (const float4*)ie, (ushort4*)buf0);

    // --- layers 1,2 gather; layer 3 fused with final combine ---
    gather_kernel<<<(GATHER_THREADS + 255) / 256, 256, 0, stream>>>(
        rowptr, ecol, dinv, (const u32*)buf0, (u32*)buf1);
    gather_kernel<<<(GATHER_THREADS + 255) / 256, 256, 0, stream>>>(
        rowptr, ecol, dinv, (const u32*)buf1, (u32*)buf2);
    gather_final_kernel<<<(GATHER_THREADS + 255) / 256, 256, 0, stream>>>(
        rowptr, ecol, dinv, (const u32*)buf1, (const u32*)buf2, ue, ie, out);
}